// Round 4
// baseline (770.729 us; speedup 1.0000x reference)
//
#include <hip/hip_runtime.h>

#define DI __device__ __forceinline__

typedef float f32x4 __attribute__((ext_vector_type(4)));
typedef float f4    __attribute__((ext_vector_type(4)));
typedef _Float16 h8 __attribute__((ext_vector_type(8)));
typedef _Float16 h4 __attribute__((ext_vector_type(4)));

// sizes
#define SEQL 512
#define BATCH 256
#define INF 300
#define HID 256
#define N2 512   // 2*HID
#define KP 320   // INF padded to multiple of 64

// pre3 layout: element (t, j, b) at byte
//   t*262144 + (j>>4)*8192 + b*32 + (j&15)*2       (f16)
// -> a 16-j slab x 256 b is 8KB; lane-contiguous for both GEMM stores and RNN loads.

DI float ftanh(float x) {
    float e = __expf(2.0f * x);
    return 1.0f - 2.0f / (e + 1.0f);
}

// ---------------- prep: build WcatT (pre-swizzled, f16) + bcat ----------------
// WTs[j][z] holds WcatT[j][k] with z = k ^ ((j&7)<<3)
__global__ void prep_kernel(const float* __restrict__ W1x, const float* __restrict__ W2x,
                            const float* __restrict__ b1, const float* __restrict__ b2,
                            _Float16* __restrict__ WTs, float* __restrict__ bcat)
{
    int idx = blockIdx.x * 256 + threadIdx.x;
    if (idx < N2 * KP) {
        int j = idx / KP, z = idx - j * KP;
        int k = z ^ ((j & 7) << 3);
        float v = 0.f;
        if (k < INF) v = (j < HID) ? W1x[k * HID + j] : W2x[k * HID + (j - HID)];
        WTs[j * KP + z] = (_Float16)v;
    }
    if (idx < N2) bcat[idx] = (idx < HID) ? b1[idx] : b2[idx - HID];
}

// ---------------- GEMM: pre3 = x @ Wcat + bcat, swapped-operand MFMA ----------------
// 128j x 128m tile, BK=64, 4 waves (2x2 of 64x64). A = Wcat^T (rows=j), B = x^T (cols=m).
// C-fragment: 4 consecutive j per lane -> coalesced 8B stores into pre3.
__global__ __launch_bounds__(256, 2) void gemm_pre(
    const float* __restrict__ x, const _Float16* __restrict__ WTs,
    const float* __restrict__ bcat, _Float16* __restrict__ pre3)
{
    __shared__ _Float16 Ab[128 * 64];  // x tile   [mr][k] xor-swizzled rows
    __shared__ _Float16 Bb[128 * 64];  // W tile   [jr][k] xor-swizzled rows (via WTs)
    const int tid = threadIdx.x;
    const int w = tid >> 6, l = tid & 63;
    const int lj = l & 15, lg = l >> 4;
    const int bm = blockIdx.x >> 2, bn = blockIdx.x & 3;
    const size_t m0 = (size_t)bm * 128;
    const int j0b = bn * 128;
    const int wj = (w >> 1) * 64, wm2 = (w & 1) * 64;

    f32x4 acc[4][4];  // [jt][mt]
#pragma unroll
    for (int a = 0; a < 4; ++a)
#pragma unroll
        for (int b = 0; b < 4; ++b) acc[a][b] = f32x4{0.f, 0.f, 0.f, 0.f};

    f4 bias4[4];
#pragma unroll
    for (int jt = 0; jt < 4; ++jt)
        bias4[jt] = *(const f4*)(bcat + j0b + wj + jt * 16 + lg * 4);

    for (int s = 0; s < 5; ++s) {
        const int k0 = s * 64;
        // W tile via global_load_lds (source pre-swizzled by prep)
#pragma unroll
        for (int q = 0; q < 4; ++q) {
            int idx = (w * 4 + q) * 64 + l;
            int jr = idx >> 3, sl = idx & 7;
            const _Float16* src = WTs + (size_t)(j0b + jr) * KP + k0 + sl * 8;
            _Float16* dst = &Bb[(w * 4 + q) * 512];
            __builtin_amdgcn_global_load_lds(
                (const __attribute__((address_space(1))) void*)src,
                (__attribute__((address_space(3))) void*)dst, 16, 0, 0);
        }
        // x tile: f32 load -> f16 convert -> swizzled ds_write
#pragma unroll
        for (int c = 0; c < 8; ++c) {
            int f = c * 256 + tid;
            int mr = f >> 4, k4 = f & 15;
            f4 v;
            if (k0 + k4 * 4 + 3 < INF)
                v = *(const f4*)(x + (m0 + mr) * INF + k0 + k4 * 4);
            else
                v = f4{0.f, 0.f, 0.f, 0.f};
            unsigned bo = (unsigned)mr * 128 + (((unsigned)k4 * 8) ^ ((mr & 7) << 4));
            *(h4*)((char*)Ab + bo) = h4{(_Float16)v[0], (_Float16)v[1], (_Float16)v[2], (_Float16)v[3]};
        }
        __syncthreads();
#pragma unroll
        for (int kk = 0; kk < 2; ++kk) {
            h8 aw[4], bx[4];
#pragma unroll
            for (int jt = 0; jt < 4; ++jt) {
                int jr = wj + jt * 16 + lj;
                unsigned bo = (unsigned)jr * 128 + (((unsigned)(kk * 64 + lg * 16)) ^ ((jr & 7) << 4));
                aw[jt] = *(const h8*)((const char*)Bb + bo);
            }
#pragma unroll
            for (int mt = 0; mt < 4; ++mt) {
                int mr = wm2 + mt * 16 + lj;
                unsigned bo = (unsigned)mr * 128 + (((unsigned)(kk * 64 + lg * 16)) ^ ((mr & 7) << 4));
                bx[mt] = *(const h8*)((const char*)Ab + bo);
            }
#pragma unroll
            for (int jt = 0; jt < 4; ++jt)
#pragma unroll
                for (int mt = 0; mt < 4; ++mt)
                    acc[jt][mt] = __builtin_amdgcn_mfma_f32_16x16x32_f16(aw[jt], bx[mt], acc[jt][mt], 0, 0, 0);
        }
        __syncthreads();
    }
    // store: 16 x 8B coalesced into pre3
    char* prc = (char*)pre3;
#pragma unroll
    for (int jt = 0; jt < 4; ++jt) {
        int slab = (j0b + wj + jt * 16) >> 4;
#pragma unroll
        for (int mt = 0; mt < 4; ++mt) {
            int M = (int)m0 + wm2 + mt * 16;
            size_t byte = (size_t)(M >> 8) * 262144 + (size_t)slab * 8192
                        + (size_t)((M & 255) + lj) * 32 + (size_t)lg * 8;
            h4 o;
#pragma unroll
            for (int i = 0; i < 4; ++i)
                o[i] = (_Float16)(acc[jt][mt][i] + bias4[jt][i]);
            *(h4*)(prc + byte) = o;
        }
    }
}

// ---------------- recurrence: 32 blocks (16 b-tiles x 2 dirs) x 4 waves x 64 j ----------------
// h in LDS, transposed layout [kk(8)][lg(4)][b(16)][i(8)] f16 = 8KB per buffer, double-buffered.
// B-frag read = lane-linear l*16 + kk*1024 (conflict-free); h-write = contiguous 512B ds_write_b64.
__global__ __launch_bounds__(256, 1) void rnn_scan(
    const float* __restrict__ W1h, const float* __restrict__ W2h,
    const _Float16* __restrict__ pre3, float* __restrict__ hcat)
{
    __shared__ char hbs[16384];  // [2][8192]
    char* hbc = hbs;
    const int tid = threadIdx.x;
    const int w = tid >> 6, l = tid & 63;
    const int lj = l & 15, lg = l >> 4;
    const int dir = blockIdx.x & 1;
    const int b0 = (int)(blockIdx.x >> 1) * 16;
    const float* Wh = dir ? W2h : W1h;
    const int j0 = w * 64;
    const int dirOff = dir ? HID : 0;

    // A = Wh^T fragments (constant across all 512 steps): lane holds
    // A[row = j0+jt*16+lj][k = kk*32+lg*8+i] = Wh[k][j]
    h8 afrag[4][8];
#pragma unroll
    for (int jt = 0; jt < 4; ++jt) {
        int jc = j0 + jt * 16 + lj;
#pragma unroll
        for (int kk = 0; kk < 8; ++kk) {
            h8 t;
#pragma unroll
            for (int i = 0; i < 8; ++i) t[i] = (_Float16)Wh[(kk * 32 + lg * 8 + i) * HID + jc];
            afrag[jt][kk] = t;
        }
    }

    // LDS addresses (one VGPR each, rest immediate)
    const unsigned rb = (unsigned)l * 16;
    const unsigned wb = (unsigned)w * 2048 + (unsigned)(lg >> 1) * 256
                      + (unsigned)lj * 16 + (unsigned)(lg & 1) * 8;

    // H(0) = 0 in buf0 (8KB)
    ((h8*)hbs)[tid] = h8{0, 0, 0, 0, 0, 0, 0, 0};
    ((h8*)hbs)[tid + 256] = h8{0, 0, 0, 0, 0, 0, 0, 0};
    __syncthreads();

    // pre3 stream: per jt one 8B load; wave loads 512B contiguous per jt.
    // dir=1 reads slabs 16..31 of each t (j in [256,512)) -> + dir*131072 bytes.
    const long long sb = dir ? -262144LL : 262144LL;
    const char* pp = (const char*)pre3 + (long long)(dir ? (SEQL - 1) : 0) * 262144
                   + (long long)dir * 131072
                   + (long long)w * 32768 + (long long)(b0 + lj) * 32 + lg * 8;
    h4 pA[4], pB[4];
#pragma unroll
    for (int jt = 0; jt < 4; ++jt) pA[jt] = *(const h4*)(pp + jt * 8192);
    pp += sb;
#pragma unroll
    for (int jt = 0; jt < 4; ++jt) pB[jt] = *(const h4*)(pp + jt * 8192);
    pp += sb;

#define RNN_STEP(RB, WB, P, DO_PF)                                                    \
    do {                                                                              \
        f32x4 acc[4];                                                                 \
        _Pragma("unroll")                                                             \
        for (int jt = 0; jt < 4; ++jt)                                                \
            _Pragma("unroll")                                                         \
            for (int i = 0; i < 4; ++i) acc[jt][i] = (float)P[jt][i];                 \
        if (DO_PF) {                                                                  \
            _Pragma("unroll")                                                         \
            for (int jt = 0; jt < 4; ++jt) P[jt] = *(const h4*)(pp + jt * 8192);      \
            pp += sb;                                                                 \
        }                                                                             \
        h8 bf[8];                                                                     \
        _Pragma("unroll")                                                             \
        for (int kk = 0; kk < 8; ++kk)                                                \
            bf[kk] = *(const h8*)(hbc + (RB) + kk * 1024 + rb);                       \
        _Pragma("unroll")                                                             \
        for (int jt = 0; jt < 4; ++jt) {                                              \
            _Pragma("unroll")                                                         \
            for (int kk = 0; kk < 8; ++kk)                                            \
                acc[jt] = __builtin_amdgcn_mfma_f32_16x16x32_f16(afrag[jt][kk], bf[kk], acc[jt], 0, 0, 0); \
        }                                                                             \
        _Pragma("unroll")                                                             \
        for (int jt = 0; jt < 4; ++jt) {                                              \
            h4 o;                                                                     \
            _Pragma("unroll")                                                         \
            for (int i = 0; i < 4; ++i) o[i] = (_Float16)ftanh(acc[jt][i]);           \
            *(h4*)(hbc + (WB) + jt * 512 + wb) = o;                                   \
        }                                                                             \
        __builtin_amdgcn_sched_barrier(0);                                            \
        asm volatile("s_waitcnt lgkmcnt(0)" ::: "memory");                            \
        __builtin_amdgcn_s_barrier();                                                 \
        __builtin_amdgcn_sched_barrier(0);                                            \
    } while (0)

    // steps 0..509 (255 pairs), all prefetching (last prefetch reads t=511, in range)
    for (int tp = 0; tp < 255; ++tp) {
        RNN_STEP(0, 8192, pA, 1);
        RNN_STEP(8192, 0, pB, 1);
    }
    // step 510: read buf0, write buf1, no prefetch
    RNN_STEP(0, 8192, pA, 0);

    // step 511: read buf1, write hcat (f32, coalesced f4)
    {
        f32x4 acc[4];
#pragma unroll
        for (int jt = 0; jt < 4; ++jt)
#pragma unroll
            for (int i = 0; i < 4; ++i) acc[jt][i] = (float)pB[jt][i];
        h8 bf[8];
#pragma unroll
        for (int kk = 0; kk < 8; ++kk)
            bf[kk] = *(const h8*)(hbc + 8192 + kk * 1024 + rb);
#pragma unroll
        for (int jt = 0; jt < 4; ++jt) {
#pragma unroll
            for (int kk = 0; kk < 8; ++kk)
                acc[jt] = __builtin_amdgcn_mfma_f32_16x16x32_f16(afrag[jt][kk], bf[kk], acc[jt], 0, 0, 0);
        }
#pragma unroll
        for (int jt = 0; jt < 4; ++jt) {
            f4 v;
#pragma unroll
            for (int i = 0; i < 4; ++i) v[i] = ftanh(acc[jt][i]);
            *(f4*)(hcat + (size_t)(b0 + lj) * N2 + dirOff + j0 + jt * 16 + lg * 4) = v;
        }
    }
#undef RNN_STEP
}

// ---------------- head: per-batch-row MLP, fp32 VALU ----------------
__global__ __launch_bounds__(256) void head_mlp(
    const float* __restrict__ hcat,
    const float* __restrict__ fc1w, const float* __restrict__ fc1b,
    const float* __restrict__ fc2w, const float* __restrict__ fc2b,
    const float* __restrict__ fsw, const float* __restrict__ fsb,
    float* __restrict__ out)
{
    __shared__ float hs[512];
    __shared__ float y1[512];
    __shared__ float red[4];
    const int b = blockIdx.x, tid = threadIdx.x;
    hs[tid] = hcat[(size_t)b * N2 + tid];
    hs[tid + 256] = hcat[(size_t)b * N2 + 256 + tid];
    __syncthreads();
    float a0 = fc1b[tid], a1 = fc1b[tid + 256];
#pragma unroll 8
    for (int k = 0; k < 512; ++k) {
        float h = hs[k];
        a0 = fmaf(h, fc1w[(size_t)k * 512 + tid], a0);
        a1 = fmaf(h, fc1w[(size_t)k * 512 + tid + 256], a1);
    }
    y1[tid] = fmaxf(a0, 0.f);
    y1[tid + 256] = fmaxf(a1, 0.f);
    __syncthreads();
    float c0 = fc2b[tid];
#pragma unroll 8
    for (int k = 0; k < 512; ++k) c0 = fmaf(y1[k], fc2w[(size_t)k * 256 + tid], c0);
    float p = fmaxf(c0, 0.f) * fsw[tid];
#pragma unroll
    for (int off = 32; off > 0; off >>= 1) p += __shfl_down(p, off);
    if ((tid & 63) == 0) red[tid >> 6] = p;
    __syncthreads();
    if (tid == 0) out[b] = ftanh(red[0] + red[1] + red[2] + red[3] + fsb[0]);
}

extern "C" void kernel_launch(void* const* d_in, const int* in_sizes, int n_in,
                              void* d_out, int out_size, void* d_ws, size_t ws_size,
                              hipStream_t stream)
{
    const float* x    = (const float*)d_in[0];
    const float* W1x  = (const float*)d_in[1];
    const float* W1h  = (const float*)d_in[2];
    const float* b1   = (const float*)d_in[3];
    const float* W2x  = (const float*)d_in[4];
    const float* W2h  = (const float*)d_in[5];
    const float* b2   = (const float*)d_in[6];
    const float* fc1w = (const float*)d_in[7];
    const float* fc1b = (const float*)d_in[8];
    const float* fc2w = (const float*)d_in[9];
    const float* fc2b = (const float*)d_in[10];
    const float* fsw  = (const float*)d_in[11];
    const float* fsb  = (const float*)d_in[12];

    char* ws = (char*)d_ws;
    size_t off = 0;
    _Float16* WTs = (_Float16*)(ws + off); off += (size_t)N2 * KP * sizeof(_Float16);
    float* bcat   = (float*)(ws + off);    off += (size_t)N2 * sizeof(float);
    float* hcat   = (float*)(ws + off);    off += (size_t)BATCH * N2 * sizeof(float);
    _Float16* pre3 = (_Float16*)(ws + off); off += (size_t)SEQL * BATCH * N2 * sizeof(_Float16);
    if (off > ws_size) return;

    prep_kernel<<<(N2 * KP + 255) / 256, 256, 0, stream>>>(W1x, W2x, b1, b2, WTs, bcat);
    gemm_pre<<<(SEQL * BATCH / 128) * (N2 / 128), 256, 0, stream>>>(x, WTs, bcat, pre3);
    rnn_scan<<<(BATCH / 16) * 2, 256, 0, stream>>>(W1h, W2h, pre3, hcat);
    head_mlp<<<BATCH, 256, 0, stream>>>(hcat, fc1w, fc1b, fc2w, fc2b, fsw, fsb, (float*)d_out);
}

// Round 5
// 663.995 us; speedup vs baseline: 1.1607x; 1.1607x over previous
//
#include <hip/hip_runtime.h>

#define DI __device__ __forceinline__

typedef float f32x4 __attribute__((ext_vector_type(4)));
typedef float f4    __attribute__((ext_vector_type(4)));
typedef _Float16 h8 __attribute__((ext_vector_type(8)));
typedef _Float16 h4 __attribute__((ext_vector_type(4)));

// sizes
#define SEQL 512
#define BATCH 256
#define INF 300
#define HID 256
#define N2 512   // 2*HID
#define KP 320   // INF padded to multiple of 64

// pre3 layout: element (t, j, b) at byte
//   t*262144 + (j>>4)*8192 + b*32 + (j&15)*2       (f16)

DI float ftanh(float x) {
    float e = __expf(2.0f * x);
    return 1.0f - 2.0f / (e + 1.0f);
}

// ---------------- prep: build WcatT (pre-swizzled, f16) + bcat ----------------
__global__ void prep_kernel(const float* __restrict__ W1x, const float* __restrict__ W2x,
                            const float* __restrict__ b1, const float* __restrict__ b2,
                            _Float16* __restrict__ WTs, float* __restrict__ bcat)
{
    int idx = blockIdx.x * 256 + threadIdx.x;
    if (idx < N2 * KP) {
        int j = idx / KP, z = idx - j * KP;
        int k = z ^ ((j & 7) << 3);
        float v = 0.f;
        if (k < INF) v = (j < HID) ? W1x[k * HID + j] : W2x[k * HID + (j - HID)];
        WTs[j * KP + z] = (_Float16)v;
    }
    if (idx < N2) bcat[idx] = (idx < HID) ? b1[idx] : b2[idx - HID];
}

// ---------------- GEMM: pre3 = x @ Wcat + bcat, swapped-operand MFMA ----------------
__global__ __launch_bounds__(256, 2) void gemm_pre(
    const float* __restrict__ x, const _Float16* __restrict__ WTs,
    const float* __restrict__ bcat, _Float16* __restrict__ pre3)
{
    __shared__ _Float16 Ab[128 * 64];  // x tile [mr][k] xor-swizzled rows
    __shared__ _Float16 Bb[128 * 64];  // W tile [jr][k] xor-swizzled rows (via WTs)
    const int tid = threadIdx.x;
    const int w = tid >> 6, l = tid & 63;
    const int lj = l & 15, lg = l >> 4;
    const int bm = blockIdx.x >> 2, bn = blockIdx.x & 3;
    const size_t m0 = (size_t)bm * 128;
    const int j0b = bn * 128;
    const int wj = (w >> 1) * 64, wm2 = (w & 1) * 64;

    f32x4 acc[4][4];  // [jt][mt]
#pragma unroll
    for (int a = 0; a < 4; ++a)
#pragma unroll
        for (int b = 0; b < 4; ++b) acc[a][b] = f32x4{0.f, 0.f, 0.f, 0.f};

    f4 bias4[4];
#pragma unroll
    for (int jt = 0; jt < 4; ++jt)
        bias4[jt] = *(const f4*)(bcat + j0b + wj + jt * 16 + lg * 4);

    for (int s = 0; s < 5; ++s) {
        const int k0 = s * 64;
#pragma unroll
        for (int q = 0; q < 4; ++q) {
            int idx = (w * 4 + q) * 64 + l;
            int jr = idx >> 3, sl = idx & 7;
            const _Float16* src = WTs + (size_t)(j0b + jr) * KP + k0 + sl * 8;
            _Float16* dst = &Bb[(w * 4 + q) * 512];
            __builtin_amdgcn_global_load_lds(
                (const __attribute__((address_space(1))) void*)src,
                (__attribute__((address_space(3))) void*)dst, 16, 0, 0);
        }
#pragma unroll
        for (int c = 0; c < 8; ++c) {
            int f = c * 256 + tid;
            int mr = f >> 4, k4 = f & 15;
            f4 v;
            if (k0 + k4 * 4 + 3 < INF)
                v = *(const f4*)(x + (m0 + mr) * INF + k0 + k4 * 4);
            else
                v = f4{0.f, 0.f, 0.f, 0.f};
            unsigned bo = (unsigned)mr * 128 + (((unsigned)k4 * 8) ^ ((mr & 7) << 4));
            *(h4*)((char*)Ab + bo) = h4{(_Float16)v[0], (_Float16)v[1], (_Float16)v[2], (_Float16)v[3]};
        }
        __syncthreads();
#pragma unroll
        for (int kk = 0; kk < 2; ++kk) {
            h8 aw[4], bx[4];
#pragma unroll
            for (int jt = 0; jt < 4; ++jt) {
                int jr = wj + jt * 16 + lj;
                unsigned bo = (unsigned)jr * 128 + (((unsigned)(kk * 64 + lg * 16)) ^ ((jr & 7) << 4));
                aw[jt] = *(const h8*)((const char*)Bb + bo);
            }
#pragma unroll
            for (int mt = 0; mt < 4; ++mt) {
                int mr = wm2 + mt * 16 + lj;
                unsigned bo = (unsigned)mr * 128 + (((unsigned)(kk * 64 + lg * 16)) ^ ((mr & 7) << 4));
                bx[mt] = *(const h8*)((const char*)Ab + bo);
            }
#pragma unroll
            for (int jt = 0; jt < 4; ++jt)
#pragma unroll
                for (int mt = 0; mt < 4; ++mt)
                    acc[jt][mt] = __builtin_amdgcn_mfma_f32_16x16x32_f16(aw[jt], bx[mt], acc[jt][mt], 0, 0, 0);
        }
        __syncthreads();
    }
    char* prc = (char*)pre3;
#pragma unroll
    for (int jt = 0; jt < 4; ++jt) {
        int slab = (j0b + wj + jt * 16) >> 4;
#pragma unroll
        for (int mt = 0; mt < 4; ++mt) {
            int M = (int)m0 + wm2 + mt * 16;
            size_t byte = (size_t)(M >> 8) * 262144 + (size_t)slab * 8192
                        + (size_t)((M & 255) + lj) * 32 + (size_t)lg * 8;
            h4 o;
#pragma unroll
            for (int i = 0; i < 4; ++i)
                o[i] = (_Float16)(acc[jt][mt][i] + bias4[jt][i]);
            *(h4*)(prc + byte) = o;
        }
    }
}

// ---------------- recurrence: 32 blocks x 8 waves (2/SIMD), 32 j per wave ----------------
// h in LDS, transposed layout [kk(8)][lg(4)][b(16)][i(8)] f16 = 8KB/buffer, double-buffered.
// Reads lane-linear l*16 + kk*1024 (conflict-free b128); writes contiguous-ish ds_write_b64.
__global__ __launch_bounds__(512, 2) void rnn_scan(
    const float* __restrict__ W1h, const float* __restrict__ W2h,
    const _Float16* __restrict__ pre3, float* __restrict__ hcat)
{
    __shared__ char hbs[16384];  // [2][8192]
    char* hbc = hbs;
    const int tid = threadIdx.x;
    const int w = tid >> 6, l = tid & 63;
    const int lj = l & 15, lg = l >> 4;
    const int dir = blockIdx.x & 1;
    const int b0 = (int)(blockIdx.x >> 1) * 16;
    const float* Wh = dir ? W2h : W1h;
    const int j0 = w * 32;
    const int dirOff = dir ? HID : 0;

    // A = Wh^T fragments (constant across all 512 steps): lane holds
    // A[row = j0+jt*16+lj][k = kk*32+lg*8+i] = Wh[k][j]   -> 64 VGPRs
    h8 afrag[2][8];
#pragma unroll
    for (int jt = 0; jt < 2; ++jt) {
        int jc = j0 + jt * 16 + lj;
#pragma unroll
        for (int kk = 0; kk < 8; ++kk) {
            h8 t;
#pragma unroll
            for (int i = 0; i < 8; ++i) t[i] = (_Float16)Wh[(kk * 32 + lg * 8 + i) * HID + jc];
            afrag[jt][kk] = t;
        }
    }

    // LDS addresses
    const unsigned rb = (unsigned)l * 16;
    // C-frag row j' = j0 + jt*16 + lg*4 + i, col b=lj -> transposed-layout byte:
    // w*1024 + (jt*2 + (lg>>1))*256 + lj*16 + (lg&1)*8 + i*2
    const unsigned wb0 = (unsigned)w * 1024 + (unsigned)(lg >> 1) * 256
                       + (unsigned)lj * 16 + (unsigned)(lg & 1) * 8;

    // H(0) = 0 in buf0 (8KB; 512 threads x 16B)
    ((h8*)hbs)[tid] = h8{0, 0, 0, 0, 0, 0, 0, 0};
    __syncthreads();

    // pre3 stream: lane loads 8B per jt; wave covers 512B contiguous per jt slab.
    const long long sb = dir ? -262144LL : 262144LL;
    const char* pp = (const char*)pre3 + (long long)(dir ? (SEQL - 1) : 0) * 262144
                   + (long long)dir * 131072
                   + (long long)w * 16384 + (long long)(b0 + lj) * 32 + lg * 8;
    h4 pA[2], pB[2];
#pragma unroll
    for (int jt = 0; jt < 2; ++jt) pA[jt] = *(const h4*)(pp + jt * 8192);
    pp += sb;
#pragma unroll
    for (int jt = 0; jt < 2; ++jt) pB[jt] = *(const h4*)(pp + jt * 8192);
    pp += sb;

#define RNN_STEP(RB, WB, P, DO_PF)                                                    \
    do {                                                                              \
        f32x4 acc0, acc1;                                                             \
        _Pragma("unroll")                                                             \
        for (int i = 0; i < 4; ++i) { acc0[i] = (float)P[0][i]; acc1[i] = (float)P[1][i]; } \
        if (DO_PF) {                                                                  \
            P[0] = *(const h4*)(pp);                                                  \
            P[1] = *(const h4*)(pp + 8192);                                           \
            pp += sb;                                                                 \
        }                                                                             \
        h8 bf[4];                                                                     \
        _Pragma("unroll")                                                             \
        for (int kk = 0; kk < 4; ++kk)                                                \
            bf[kk] = *(const h8*)(hbc + (RB) + kk * 1024 + rb);                       \
        _Pragma("unroll")                                                             \
        for (int kk = 0; kk < 4; ++kk) {                                              \
            acc0 = __builtin_amdgcn_mfma_f32_16x16x32_f16(afrag[0][kk], bf[kk], acc0, 0, 0, 0); \
            acc1 = __builtin_amdgcn_mfma_f32_16x16x32_f16(afrag[1][kk], bf[kk], acc1, 0, 0, 0); \
        }                                                                             \
        _Pragma("unroll")                                                             \
        for (int kk = 0; kk < 4; ++kk)                                                \
            bf[kk] = *(const h8*)(hbc + (RB) + (kk + 4) * 1024 + rb);                 \
        _Pragma("unroll")                                                             \
        for (int kk = 0; kk < 4; ++kk) {                                              \
            acc0 = __builtin_amdgcn_mfma_f32_16x16x32_f16(afrag[0][kk + 4], bf[kk], acc0, 0, 0, 0); \
            acc1 = __builtin_amdgcn_mfma_f32_16x16x32_f16(afrag[1][kk + 4], bf[kk], acc1, 0, 0, 0); \
        }                                                                             \
        h4 o0, o1;                                                                    \
        _Pragma("unroll")                                                             \
        for (int i = 0; i < 4; ++i) {                                                 \
            o0[i] = (_Float16)ftanh(acc0[i]);                                         \
            o1[i] = (_Float16)ftanh(acc1[i]);                                         \
        }                                                                             \
        *(h4*)(hbc + (WB) + wb0) = o0;                                                \
        *(h4*)(hbc + (WB) + wb0 + 512) = o1;                                          \
        __builtin_amdgcn_sched_barrier(0);                                            \
        asm volatile("s_waitcnt lgkmcnt(0)" ::: "memory");                            \
        __builtin_amdgcn_s_barrier();                                                 \
        __builtin_amdgcn_sched_barrier(0);                                            \
    } while (0)

    // steps 0..509 (255 pairs), prefetching (last prefetch reads t=511, in range)
    for (int tp = 0; tp < 255; ++tp) {
        RNN_STEP(0, 8192, pA, 1);
        RNN_STEP(8192, 0, pB, 1);
    }
    // step 510: read buf0, write buf1, no prefetch
    RNN_STEP(0, 8192, pA, 0);

    // step 511: read buf1, write hcat (f32, coalesced f4)
    {
        f32x4 acc0, acc1;
#pragma unroll
        for (int i = 0; i < 4; ++i) { acc0[i] = (float)pB[0][i]; acc1[i] = (float)pB[1][i]; }
        h8 bf[8];
#pragma unroll
        for (int kk = 0; kk < 8; ++kk)
            bf[kk] = *(const h8*)(hbc + 8192 + kk * 1024 + rb);
#pragma unroll
        for (int kk = 0; kk < 8; ++kk) {
            acc0 = __builtin_amdgcn_mfma_f32_16x16x32_f16(afrag[0][kk], bf[kk], acc0, 0, 0, 0);
            acc1 = __builtin_amdgcn_mfma_f32_16x16x32_f16(afrag[1][kk], bf[kk], acc1, 0, 0, 0);
        }
        f4 v0, v1;
#pragma unroll
        for (int i = 0; i < 4; ++i) { v0[i] = ftanh(acc0[i]); v1[i] = ftanh(acc1[i]); }
        float* hc = hcat + (size_t)(b0 + lj) * N2 + dirOff + j0 + lg * 4;
        *(f4*)hc = v0;
        *(f4*)(hc + 16) = v1;
    }
#undef RNN_STEP
}

// ---------------- head: per-batch-row MLP, fp32 VALU ----------------
__global__ __launch_bounds__(256) void head_mlp(
    const float* __restrict__ hcat,
    const float* __restrict__ fc1w, const float* __restrict__ fc1b,
    const float* __restrict__ fc2w, const float* __restrict__ fc2b,
    const float* __restrict__ fsw, const float* __restrict__ fsb,
    float* __restrict__ out)
{
    __shared__ float hs[512];
    __shared__ float y1[512];
    __shared__ float red[4];
    const int b = blockIdx.x, tid = threadIdx.x;
    hs[tid] = hcat[(size_t)b * N2 + tid];
    hs[tid + 256] = hcat[(size_t)b * N2 + 256 + tid];
    __syncthreads();
    float a0 = fc1b[tid], a1 = fc1b[tid + 256];
#pragma unroll 8
    for (int k = 0; k < 512; ++k) {
        float h = hs[k];
        a0 = fmaf(h, fc1w[(size_t)k * 512 + tid], a0);
        a1 = fmaf(h, fc1w[(size_t)k * 512 + tid + 256], a1);
    }
    y1[tid] = fmaxf(a0, 0.f);
    y1[tid + 256] = fmaxf(a1, 0.f);
    __syncthreads();
    float c0 = fc2b[tid];
#pragma unroll 8
    for (int k = 0; k < 512; ++k) c0 = fmaf(y1[k], fc2w[(size_t)k * 256 + tid], c0);
    float p = fmaxf(c0, 0.f) * fsw[tid];
#pragma unroll
    for (int off = 32; off > 0; off >>= 1) p += __shfl_down(p, off);
    if ((tid & 63) == 0) red[tid >> 6] = p;
    __syncthreads();
    if (tid == 0) out[b] = ftanh(red[0] + red[1] + red[2] + red[3] + fsb[0]);
}

extern "C" void kernel_launch(void* const* d_in, const int* in_sizes, int n_in,
                              void* d_out, int out_size, void* d_ws, size_t ws_size,
                              hipStream_t stream)
{
    const float* x    = (const float*)d_in[0];
    const float* W1x  = (const float*)d_in[1];
    const float* W1h  = (const float*)d_in[2];
    const float* b1   = (const float*)d_in[3];
    const float* W2x  = (const float*)d_in[4];
    const float* W2h  = (const float*)d_in[5];
    const float* b2   = (const float*)d_in[6];
    const float* fc1w = (const float*)d_in[7];
    const float* fc1b = (const float*)d_in[8];
    const float* fc2w = (const float*)d_in[9];
    const float* fc2b = (const float*)d_in[10];
    const float* fsw  = (const float*)d_in[11];
    const float* fsb  = (const float*)d_in[12];

    char* ws = (char*)d_ws;
    size_t off = 0;
    _Float16* WTs = (_Float16*)(ws + off); off += (size_t)N2 * KP * sizeof(_Float16);
    float* bcat   = (float*)(ws + off);    off += (size_t)N2 * sizeof(float);
    float* hcat   = (float*)(ws + off);    off += (size_t)BATCH * N2 * sizeof(float);
    _Float16* pre3 = (_Float16*)(ws + off); off += (size_t)SEQL * BATCH * N2 * sizeof(_Float16);
    if (off > ws_size) return;

    prep_kernel<<<(N2 * KP + 255) / 256, 256, 0, stream>>>(W1x, W2x, b1, b2, WTs, bcat);
    gemm_pre<<<(SEQL * BATCH / 128) * (N2 / 128), 256, 0, stream>>>(x, WTs, bcat, pre3);
    rnn_scan<<<(BATCH / 16) * 2, 512, 0, stream>>>(W1h, W2h, pre3, hcat);
    head_mlp<<<BATCH, 256, 0, stream>>>(hcat, fc1w, fc1b, fc2w, fc2b, fsw, fsb, (float*)d_out);
}

// Round 6
// 483.851 us; speedup vs baseline: 1.5929x; 1.3723x over previous
//
#include <hip/hip_runtime.h>

#define DI __device__ __forceinline__

typedef float f32x4 __attribute__((ext_vector_type(4)));
typedef float f4    __attribute__((ext_vector_type(4)));
typedef _Float16 h8 __attribute__((ext_vector_type(8)));
typedef _Float16 h4 __attribute__((ext_vector_type(4)));

// sizes
#define SEQL 512
#define BATCH 256
#define INF 300
#define HID 256
#define N2 512   // 2*HID
#define KP 320   // INF padded to multiple of 64

// pre3 layout: element (t, j, b) at byte
//   t*262144 + (j>>4)*8192 + b*32 + (j&15)*2       (f16)

// tanh = 1 - 2/(1+exp2(x*2*log2e)); exp2->inf => 1, exp2->0 => -1. ~1ulp, fine for f16 h.
DI float ftanh(float x) {
    float e = __builtin_amdgcn_exp2f(x * 2.8853900817779268f);
    return fmaf(-2.0f, __builtin_amdgcn_rcpf(e + 1.0f), 1.0f);
}

// ---------------- prep: build WcatT (pre-swizzled, f16) + bcat ----------------
__global__ void prep_kernel(const float* __restrict__ W1x, const float* __restrict__ W2x,
                            const float* __restrict__ b1, const float* __restrict__ b2,
                            _Float16* __restrict__ WTs, float* __restrict__ bcat)
{
    int idx = blockIdx.x * 256 + threadIdx.x;
    if (idx < N2 * KP) {
        int j = idx / KP, z = idx - j * KP;
        int k = z ^ ((j & 7) << 3);
        float v = 0.f;
        if (k < INF) v = (j < HID) ? W1x[k * HID + j] : W2x[k * HID + (j - HID)];
        WTs[j * KP + z] = (_Float16)v;
    }
    if (idx < N2) bcat[idx] = (idx < HID) ? b1[idx] : b2[idx - HID];
}

// ---------------- GEMM: pre3 = x @ Wcat + bcat, swapped-operand MFMA ----------------
// XCD-grouped swizzle: xcd=bid&7 owns bm in [xcd*128, xcd*128+128); the 4 bn-blocks of
// one bm are consecutive on the SAME XCD -> x tile L2-hits for 3 of 4, W stays L2-resident.
__global__ __launch_bounds__(256, 2) void gemm_pre(
    const float* __restrict__ x, const _Float16* __restrict__ WTs,
    const float* __restrict__ bcat, _Float16* __restrict__ pre3)
{
    __shared__ _Float16 Ab[128 * 64];  // x tile [mr][k] xor-swizzled rows
    __shared__ _Float16 Bb[128 * 64];  // W tile [jr][k] xor-swizzled rows (via WTs)
    const int tid = threadIdx.x;
    const int w = tid >> 6, l = tid & 63;
    const int lj = l & 15, lg = l >> 4;
    const int bid = blockIdx.x;
    const int xcd = bid & 7;
    const int idx0 = bid >> 3;
    const int bn = idx0 & 3;
    const int bm = xcd * 128 + (idx0 >> 2);
    const size_t m0 = (size_t)bm * 128;
    const int j0b = bn * 128;
    const int wj = (w >> 1) * 64, wm2 = (w & 1) * 64;

    f32x4 acc[4][4];  // [jt][mt]
#pragma unroll
    for (int a = 0; a < 4; ++a)
#pragma unroll
        for (int b = 0; b < 4; ++b) acc[a][b] = f32x4{0.f, 0.f, 0.f, 0.f};

    f4 bias4[4];
#pragma unroll
    for (int jt = 0; jt < 4; ++jt)
        bias4[jt] = *(const f4*)(bcat + j0b + wj + jt * 16 + lg * 4);

    for (int s = 0; s < 5; ++s) {
        const int k0 = s * 64;
#pragma unroll
        for (int q = 0; q < 4; ++q) {
            int idx = (w * 4 + q) * 64 + l;
            int jr = idx >> 3, sl = idx & 7;
            const _Float16* src = WTs + (size_t)(j0b + jr) * KP + k0 + sl * 8;
            _Float16* dst = &Bb[(w * 4 + q) * 512];
            __builtin_amdgcn_global_load_lds(
                (const __attribute__((address_space(1))) void*)src,
                (__attribute__((address_space(3))) void*)dst, 16, 0, 0);
        }
#pragma unroll
        for (int c = 0; c < 8; ++c) {
            int f = c * 256 + tid;
            int mr = f >> 4, k4 = f & 15;
            f4 v;
            if (k0 + k4 * 4 + 3 < INF)
                v = *(const f4*)(x + (m0 + mr) * INF + k0 + k4 * 4);
            else
                v = f4{0.f, 0.f, 0.f, 0.f};
            unsigned bo = (unsigned)mr * 128 + (((unsigned)k4 * 8) ^ ((mr & 7) << 4));
            *(h4*)((char*)Ab + bo) = h4{(_Float16)v[0], (_Float16)v[1], (_Float16)v[2], (_Float16)v[3]};
        }
        __syncthreads();
#pragma unroll
        for (int kk = 0; kk < 2; ++kk) {
            h8 aw[4], bx[4];
#pragma unroll
            for (int jt = 0; jt < 4; ++jt) {
                int jr = wj + jt * 16 + lj;
                unsigned bo = (unsigned)jr * 128 + (((unsigned)(kk * 64 + lg * 16)) ^ ((jr & 7) << 4));
                aw[jt] = *(const h8*)((const char*)Bb + bo);
            }
#pragma unroll
            for (int mt = 0; mt < 4; ++mt) {
                int mr = wm2 + mt * 16 + lj;
                unsigned bo = (unsigned)mr * 128 + (((unsigned)(kk * 64 + lg * 16)) ^ ((mr & 7) << 4));
                bx[mt] = *(const h8*)((const char*)Ab + bo);
            }
#pragma unroll
            for (int jt = 0; jt < 4; ++jt)
#pragma unroll
                for (int mt = 0; mt < 4; ++mt)
                    acc[jt][mt] = __builtin_amdgcn_mfma_f32_16x16x32_f16(aw[jt], bx[mt], acc[jt][mt], 0, 0, 0);
        }
        __syncthreads();
    }
    char* prc = (char*)pre3;
#pragma unroll
    for (int jt = 0; jt < 4; ++jt) {
        int slab = (j0b + wj + jt * 16) >> 4;
#pragma unroll
        for (int mt = 0; mt < 4; ++mt) {
            int M = (int)m0 + wm2 + mt * 16;
            size_t byte = (size_t)(M >> 8) * 262144 + (size_t)slab * 8192
                        + (size_t)((M & 255) + lj) * 32 + (size_t)lg * 8;
            h4 o;
#pragma unroll
            for (int i = 0; i < 4; ++i)
                o[i] = (_Float16)(acc[jt][mt][i] + bias4[jt][i]);
            *(h4*)(prc + byte) = o;
        }
    }
}

// ---------------- recurrence: 32 blocks x 8 waves (2/SIMD), 32 j per wave ----------------
// h in LDS, transposed layout [kk(8)][lg(4)][b(16)][i(8)] f16 = 8KB/buffer, double-buffered.
// Per step: issue all 8 conflict-free b128 reads first, acc0 MFMA chain -> tanh0/write0
// overlaps acc1 chain, one barrier per step.
__global__ __launch_bounds__(512, 2) void rnn_scan(
    const float* __restrict__ W1h, const float* __restrict__ W2h,
    const _Float16* __restrict__ pre3, float* __restrict__ hcat)
{
    __shared__ char hbs[16384];  // [2][8192]
    char* hbc = hbs;
    const int tid = threadIdx.x;
    const int w = tid >> 6, l = tid & 63;
    const int lj = l & 15, lg = l >> 4;
    const int dir = blockIdx.x & 1;
    const int b0 = (int)(blockIdx.x >> 1) * 16;
    const float* Wh = dir ? W2h : W1h;
    const int j0 = w * 32;
    const int dirOff = dir ? HID : 0;

    // A = Wh^T fragments (step-constant, 64 VGPR): A[row=j0+jt*16+lj][k=kk*32+lg*8+i]
    h8 afrag[2][8];
#pragma unroll
    for (int jt = 0; jt < 2; ++jt) {
        int jc = j0 + jt * 16 + lj;
#pragma unroll
        for (int kk = 0; kk < 8; ++kk) {
            h8 t;
#pragma unroll
            for (int i = 0; i < 8; ++i) t[i] = (_Float16)Wh[(kk * 32 + lg * 8 + i) * HID + jc];
            afrag[jt][kk] = t;
        }
    }

    // LDS addresses
    const unsigned rb = (unsigned)l * 16;
    const unsigned wb0 = (unsigned)w * 1024 + (unsigned)(lg >> 1) * 256
                       + (unsigned)lj * 16 + (unsigned)(lg & 1) * 8;

    // H(0) = 0 in buf0 (8KB; 512 threads x 16B)
    ((h8*)hbs)[tid] = h8{0, 0, 0, 0, 0, 0, 0, 0};
    __syncthreads();

    // pre3 stream: lane loads 8B per jt; wave covers 512B contiguous per jt slab.
    const long long sb = dir ? -262144LL : 262144LL;
    const char* pp = (const char*)pre3 + (long long)(dir ? (SEQL - 1) : 0) * 262144
                   + (long long)dir * 131072
                   + (long long)w * 16384 + (long long)(b0 + lj) * 32 + lg * 8;
    h4 pA[2], pB[2];
#pragma unroll
    for (int jt = 0; jt < 2; ++jt) pA[jt] = *(const h4*)(pp + jt * 8192);
    pp += sb;
#pragma unroll
    for (int jt = 0; jt < 2; ++jt) pB[jt] = *(const h4*)(pp + jt * 8192);
    pp += sb;

#define RNN_STEP(RB, WB, P, DO_PF)                                                    \
    do {                                                                              \
        h8 bf[8];                                                                     \
        _Pragma("unroll")                                                             \
        for (int kk = 0; kk < 8; ++kk)                                                \
            bf[kk] = *(const h8*)(hbc + (RB) + kk * 1024 + rb);                       \
        f32x4 acc0, acc1;                                                             \
        _Pragma("unroll")                                                             \
        for (int i = 0; i < 4; ++i) { acc0[i] = (float)P[0][i]; acc1[i] = (float)P[1][i]; } \
        if (DO_PF) {                                                                  \
            P[0] = *(const h4*)(pp);                                                  \
            P[1] = *(const h4*)(pp + 8192);                                           \
            pp += sb;                                                                 \
        }                                                                             \
        _Pragma("unroll")                                                             \
        for (int kk = 0; kk < 8; ++kk)                                                \
            acc0 = __builtin_amdgcn_mfma_f32_16x16x32_f16(afrag[0][kk], bf[kk], acc0, 0, 0, 0); \
        h4 o0;                                                                        \
        _Pragma("unroll")                                                             \
        for (int i = 0; i < 4; ++i) o0[i] = (_Float16)ftanh(acc0[i]);                 \
        *(h4*)(hbc + (WB) + wb0) = o0;                                                \
        _Pragma("unroll")                                                             \
        for (int kk = 0; kk < 8; ++kk)                                                \
            acc1 = __builtin_amdgcn_mfma_f32_16x16x32_f16(afrag[1][kk], bf[kk], acc1, 0, 0, 0); \
        h4 o1;                                                                        \
        _Pragma("unroll")                                                             \
        for (int i = 0; i < 4; ++i) o1[i] = (_Float16)ftanh(acc1[i]);                 \
        *(h4*)(hbc + (WB) + wb0 + 512) = o1;                                          \
        __builtin_amdgcn_sched_barrier(0);                                            \
        asm volatile("s_waitcnt lgkmcnt(0)" ::: "memory");                            \
        __builtin_amdgcn_s_barrier();                                                 \
        __builtin_amdgcn_sched_barrier(0);                                            \
    } while (0)

    // steps 0..509 (255 pairs), prefetching (last prefetch reads t=511, in range)
    for (int tp = 0; tp < 255; ++tp) {
        RNN_STEP(0, 8192, pA, 1);
        RNN_STEP(8192, 0, pB, 1);
    }
    // step 510: read buf0, write buf1, no prefetch
    RNN_STEP(0, 8192, pA, 0);

    // step 511: read buf1, write hcat (f32, coalesced f4)
    {
        f32x4 acc0, acc1;
#pragma unroll
        for (int i = 0; i < 4; ++i) { acc0[i] = (float)pB[0][i]; acc1[i] = (float)pB[1][i]; }
        h8 bf[8];
#pragma unroll
        for (int kk = 0; kk < 8; ++kk)
            bf[kk] = *(const h8*)(hbc + 8192 + kk * 1024 + rb);
#pragma unroll
        for (int kk = 0; kk < 8; ++kk) {
            acc0 = __builtin_amdgcn_mfma_f32_16x16x32_f16(afrag[0][kk], bf[kk], acc0, 0, 0, 0);
            acc1 = __builtin_amdgcn_mfma_f32_16x16x32_f16(afrag[1][kk], bf[kk], acc1, 0, 0, 0);
        }
        f4 v0, v1;
#pragma unroll
        for (int i = 0; i < 4; ++i) { v0[i] = ftanh(acc0[i]); v1[i] = ftanh(acc1[i]); }
        float* hc = hcat + (size_t)(b0 + lj) * N2 + dirOff + j0 + lg * 4;
        *(f4*)hc = v0;
        *(f4*)(hc + 16) = v1;
    }
#undef RNN_STEP
}

// ---------------- head: per-batch-row MLP, fp32 VALU ----------------
__global__ __launch_bounds__(256) void head_mlp(
    const float* __restrict__ hcat,
    const float* __restrict__ fc1w, const float* __restrict__ fc1b,
    const float* __restrict__ fc2w, const float* __restrict__ fc2b,
    const float* __restrict__ fsw, const float* __restrict__ fsb,
    float* __restrict__ out)
{
    __shared__ float hs[512];
    __shared__ float y1[512];
    __shared__ float red[4];
    const int b = blockIdx.x, tid = threadIdx.x;
    hs[tid] = hcat[(size_t)b * N2 + tid];
    hs[tid + 256] = hcat[(size_t)b * N2 + 256 + tid];
    __syncthreads();
    float a0 = fc1b[tid], a1 = fc1b[tid + 256];
#pragma unroll 8
    for (int k = 0; k < 512; ++k) {
        float h = hs[k];
        a0 = fmaf(h, fc1w[(size_t)k * 512 + tid], a0);
        a1 = fmaf(h, fc1w[(size_t)k * 512 + tid + 256], a1);
    }
    y1[tid] = fmaxf(a0, 0.f);
    y1[tid + 256] = fmaxf(a1, 0.f);
    __syncthreads();
    float c0 = fc2b[tid];
#pragma unroll 8
    for (int k = 0; k < 512; ++k) c0 = fmaf(y1[k], fc2w[(size_t)k * 256 + tid], c0);
    float p = fmaxf(c0, 0.f) * fsw[tid];
#pragma unroll
    for (int off = 32; off > 0; off >>= 1) p += __shfl_down(p, off);
    if ((tid & 63) == 0) red[tid >> 6] = p;
    __syncthreads();
    if (tid == 0) out[b] = ftanh(red[0] + red[1] + red[2] + red[3] + fsb[0]);
}

extern "C" void kernel_launch(void* const* d_in, const int* in_sizes, int n_in,
                              void* d_out, int out_size, void* d_ws, size_t ws_size,
                              hipStream_t stream)
{
    const float* x    = (const float*)d_in[0];
    const float* W1x  = (const float*)d_in[1];
    const float* W1h  = (const float*)d_in[2];
    const float* b1   = (const float*)d_in[3];
    const float* W2x  = (const float*)d_in[4];
    const float* W2h  = (const float*)d_in[5];
    const float* b2   = (const float*)d_in[6];
    const float* fc1w = (const float*)d_in[7];
    const float* fc1b = (const float*)d_in[8];
    const float* fc2w = (const float*)d_in[9];
    const float* fc2b = (const float*)d_in[10];
    const float* fsw  = (const float*)d_in[11];
    const float* fsb  = (const float*)d_in[12];

    char* ws = (char*)d_ws;
    size_t off = 0;
    _Float16* WTs = (_Float16*)(ws + off); off += (size_t)N2 * KP * sizeof(_Float16);
    float* bcat   = (float*)(ws + off);    off += (size_t)N2 * sizeof(float);
    float* hcat   = (float*)(ws + off);    off += (size_t)BATCH * N2 * sizeof(float);
    _Float16* pre3 = (_Float16*)(ws + off); off += (size_t)SEQL * BATCH * N2 * sizeof(_Float16);
    if (off > ws_size) return;

    prep_kernel<<<(N2 * KP + 255) / 256, 256, 0, stream>>>(W1x, W2x, b1, b2, WTs, bcat);
    gemm_pre<<<(SEQL * BATCH / 128) * (N2 / 128), 256, 0, stream>>>(x, WTs, bcat, pre3);
    rnn_scan<<<(BATCH / 16) * 2, 512, 0, stream>>>(W1h, W2h, pre3, hcat);
    head_mlp<<<BATCH, 256, 0, stream>>>(hcat, fc1w, fc1b, fc2w, fc2b, fsw, fsb, (float*)d_out);
}